// Round 10
// baseline (3356.001 us; speedup 1.0000x reference)
//
#include <hip/hip_runtime.h>
#include <math.h>

#define BATCH 16
#define ISZ   1024
#define MSZ   32768
#define DSZ   128
#define TOPK  32
#define EPSV  1e-8f
#define NCHUNK 32              // chunks per batch for partial top-k
#define CHUNK  (MSZ / NCHUNK)  // 1024 rows per chunk
#define CPL    (CHUNK / 64)    // 16 sims per lane
#define REPS  32               // diagnostic amplification (idempotent reps)

typedef float f32x4 __attribute__((ext_vector_type(4)));

// ---------------- k0: projections (wv, rq) -----------------------------------
// grid 256, block 256. 4096 dot-tasks over 1024 waves, 4 tasks/wave.
__global__ __launch_bounds__(256)
void k0_proj(const float* __restrict__ x,
             const float* __restrict__ Ww, const float* __restrict__ bw,
             const float* __restrict__ Wr, const float* __restrict__ br,
             float* __restrict__ wv, float* __restrict__ rq) {
    const int tid = threadIdx.x, bid = blockIdx.x;
    const int lane = tid & 63, wid = tid >> 6;
    for (int rep = 0; rep < REPS; ++rep) {
        asm volatile("" ::: "memory");   // defeat cross-rep CSE/hoist
        int wg = bid * 4 + wid;
        #pragma unroll
        for (int t = 0; t < 4; ++t) {
            int T   = wg * 4 + t;
            int b   = T >> 8;
            int d   = (T >> 1) & 127;
            int mat = T & 1;
            const float* wrow = (mat ? Wr : Ww) + (size_t)d * ISZ;
            const float* xr   = x + (size_t)b * ISZ;
            float a = 0.f;
            #pragma unroll
            for (int i = 0; i < 16; ++i)
                a = fmaf(xr[lane + 64 * i], wrow[lane + 64 * i], a);
            for (int off = 32; off; off >>= 1) a += __shfl_down(a, off);
            if (lane == 0) {
                if (mat) rq[b * DSZ + d] = a + br[d];
                else     wv[b * DSZ + d] = a + bw[d];
            }
        }
    }
}

// ---------------- k1: similarities (+ fused row norm) ------------------------
// grid 256, block 256, tid<128 active (exact fused03 phase-1 shape).
__global__ __launch_bounds__(256)
void k1_sim(const float* __restrict__ rq,
            const float* __restrict__ memory, float* __restrict__ sim) {
    __shared__ float qn_s[BATCH];
    const int tid = threadIdx.x, bid = blockIdx.x;
    for (int rep = 0; rep < REPS; ++rep) {
        asm volatile("" ::: "memory");
        if (tid < 128) {
            int b0 = tid >> 3, seg = tid & 7;
            float a = 0.f;
            #pragma unroll
            for (int j = 0; j < 16; ++j) {
                float v = rq[b0 * DSZ + seg * 16 + j];
                a = fmaf(v, v, a);
            }
            for (int off = 4; off; off >>= 1) a += __shfl_down(a, off, 8);
            if (seg == 0) qn_s[b0] = fmaxf(sqrtf(a), EPSV);
        }
        __syncthreads();
        if (tid < 128) {
            int r = bid * 128 + tid;
            const f32x4* rowp = (const f32x4*)(memory + (size_t)r * DSZ);
            const f32x4* q4   = (const f32x4*)rq;
            float acc[BATCH];
            #pragma unroll
            for (int b = 0; b < BATCH; ++b) acc[b] = 0.f;
            float nrm = 0.f;
            f32x4 v[16];
            #pragma unroll
            for (int half = 0; half < 2; ++half) {
                #pragma unroll
                for (int j = 0; j < 16; ++j) v[j] = rowp[half * 16 + j];
                #pragma unroll
                for (int j = 0; j < 16; ++j) {
                    f32x4 w = v[j];
                    nrm = fmaf(w.x, w.x, fmaf(w.y, w.y, fmaf(w.z, w.z, fmaf(w.w, w.w, nrm))));
                    #pragma unroll
                    for (int b = 0; b < BATCH; ++b) {
                        f32x4 q = q4[b * 32 + half * 16 + j];
                        acc[b] = fmaf(w.x, q.x, fmaf(w.y, q.y, fmaf(w.z, q.z, fmaf(w.w, q.w, acc[b]))));
                    }
                }
            }
            float mnr = fmaxf(sqrtf(nrm), EPSV);
            #pragma unroll
            for (int b = 0; b < BATCH; ++b)
                sim[(size_t)b * MSZ + r] = acc[b] / (qn_s[b] * mnr);
        }
        __syncthreads();
    }
}

// ---------------- k2: per-wave partial top-32 --------------------------------
// grid 256, block 256, waves 0/1 active (exact fused03 phase-2 shape).
__global__ __launch_bounds__(256)
void k2_ptopk(const float* __restrict__ sim,
              float* __restrict__ cand_v, int* __restrict__ cand_i) {
    const int tid = threadIdx.x, bid = blockIdx.x;
    const int lane = tid & 63, wid = tid >> 6;
    for (int rep = 0; rep < REPS; ++rep) {
        asm volatile("" ::: "memory");
        if (wid < 2) {
            int task  = bid * 2 + wid;   // 0..511
            int b     = task >> 5;
            int chunk = task & 31;
            int base  = chunk * CHUNK;
            const float* s = sim + (size_t)b * MSZ + base;

            float val[CPL];
            #pragma unroll
            for (int i = 0; i < CPL; ++i) val[i] = s[i * 64 + lane];

            float keep_v = -INFINITY; int keep_i = 0x7FFFFFFF;
            for (int k = 0; k < TOPK; ++k) {
                float lv = -INFINITY; int li = 0x7FFFFFFF;
                #pragma unroll
                for (int i = 0; i < CPL; ++i) {
                    int gi = base + i * 64 + lane;
                    bool better = val[i] > lv;
                    lv = better ? val[i] : lv;
                    li = better ? gi : li;
                }
                float bv = lv; int bi = li;
                #pragma unroll
                for (int off = 32; off; off >>= 1) {
                    float ov = __shfl_xor(bv, off);
                    int   oi = __shfl_xor(bi, off);
                    if (ov > bv || (ov == bv && oi < bi)) { bv = ov; bi = oi; }
                }
                if (lane == k) { keep_v = bv; keep_i = bi; }
                #pragma unroll
                for (int i = 0; i < CPL; ++i) {
                    int gi = base + i * 64 + lane;
                    val[i] = (gi == bi) ? -INFINITY : val[i];
                }
            }
            if (lane < TOPK) {
                cand_v[task * TOPK + lane] = keep_v;
                cand_i[task * TOPK + lane] = keep_i;
            }
        }
    }
}

// ---------------- k3: merge -> exact top-32; retrieved; u; out ---------------
// grid 256, bid<16 active (exact fused03 phase-3 shape).
__global__ __launch_bounds__(256)
void k3_merge(const float* __restrict__ cand_v, const int* __restrict__ cand_i,
              const float* __restrict__ memory, const float* __restrict__ wv,
              const float* __restrict__ Wo, const float* __restrict__ bo,
              float* __restrict__ out, float* __restrict__ u) {
    __shared__ int   topi[TOPK];
    __shared__ float r_s[DSZ];
    __shared__ float s_sh;
    const int tid = threadIdx.x, bid = blockIdx.x;
    const int lane = tid & 63;
    if (bid >= BATCH) return;
    const int b = bid;
    const int NC = NCHUNK * TOPK;   // 1024 candidates
    const int PL = NC / 64;         // 16 per lane
    for (int rep = 0; rep < REPS; ++rep) {
        asm volatile("" ::: "memory");
        __syncthreads();
        if (tid < 64) {
            float val[PL]; int idx[PL];
            #pragma unroll
            for (int i = 0; i < PL; ++i) {
                val[i] = cand_v[b * NC + i * 64 + lane];
                idx[i] = cand_i[b * NC + i * 64 + lane];
            }
            for (int k = 0; k < TOPK; ++k) {
                float lv = -INFINITY; int li = 0x7FFFFFFF;
                #pragma unroll
                for (int i = 0; i < PL; ++i) {
                    bool better = (val[i] > lv) || (val[i] == lv && idx[i] < li);
                    lv = better ? val[i] : lv;
                    li = better ? idx[i] : li;
                }
                float bv = lv; int bi = li;
                #pragma unroll
                for (int off = 32; off; off >>= 1) {
                    float ov = __shfl_xor(bv, off);
                    int   oi = __shfl_xor(bi, off);
                    if (ov > bv || (ov == bv && oi < bi)) { bv = ov; bi = oi; }
                }
                if (lane == k) topi[lane] = bi;
                #pragma unroll
                for (int i = 0; i < PL; ++i)
                    val[i] = (idx[i] == bi) ? -INFINITY : val[i];
            }
        }
        __syncthreads();
        if (tid < DSZ) {
            float rsum = 0.f;
            for (int k = 0; k < TOPK; ++k)
                rsum += memory[(size_t)topi[k] * DSZ + tid];
            r_s[tid] = rsum;
        }
        __syncthreads();
        if (tid < 64) {
            float a = wv[b * DSZ + tid] * r_s[tid] + wv[b * DSZ + 64 + tid] * r_s[64 + tid];
            for (int off = 32; off; off >>= 1) a += __shfl_down(a, off);
            if (tid == 0) s_sh = 1.f / (1.f + expf(-a));
        }
        __syncthreads();
        if (tid < DSZ) u[b * DSZ + tid] = s_sh * wv[b * DSZ + tid];

        const f32x4* r4 = (const f32x4*)r_s;
        for (int i = tid; i < ISZ; i += 256) {
            const f32x4* w4 = (const f32x4*)(Wo + (size_t)i * DSZ);
            float acc = 0.f;
            #pragma unroll 8
            for (int j = 0; j < 32; ++j) {
                f32x4 w = w4[j];
                f32x4 r = r4[j];
                acc = fmaf(w.x, r.x, fmaf(w.y, r.y, fmaf(w.z, r.z, fmaf(w.w, r.w, acc))));
            }
            out[b * ISZ + i] = acc + bo[i];
        }
    }
}

// ---------------- k4: new_memory = memory + u[b] (unamplified) ---------------
__global__ void k4_bcast(const float* __restrict__ memory, const float* __restrict__ u,
                         float* __restrict__ out_nm) {
    __shared__ f32x4 u_s[BATCH * DSZ / 4];   // 8 KiB
    int tid = threadIdx.x;
    const f32x4* u4 = (const f32x4*)u;
    for (int i = tid; i < BATCH * DSZ / 4; i += 256) u_s[i] = u4[i];
    __syncthreads();
    size_t f = (size_t)blockIdx.x * 256 + tid;
    f32x4 m4 = ((const f32x4*)memory)[f];
    int d4 = (int)(f & 31);
    f32x4* o = (f32x4*)out_nm;
    #pragma unroll
    for (int b = 0; b < BATCH; ++b)
        o[(size_t)b * (MSZ * DSZ / 4) + f] = m4 + u_s[b * 32 + d4];
}

extern "C" void kernel_launch(void* const* d_in, const int* in_sizes, int n_in,
                              void* d_out, int out_size, void* d_ws, size_t ws_size,
                              hipStream_t stream) {
    const float* x      = (const float*)d_in[0];
    const float* memory = (const float*)d_in[1];
    const float* Ww     = (const float*)d_in[2];
    const float* bw     = (const float*)d_in[3];
    const float* Wr     = (const float*)d_in[4];
    const float* br     = (const float*)d_in[5];
    const float* Wo     = (const float*)d_in[6];
    const float* bo     = (const float*)d_in[7];

    float* out    = (float*)d_out;            // [16,1024]
    float* out_nm = out + BATCH * ISZ;        // [16,32768,128]

    float* ws     = (float*)d_ws;
    float* wv     = ws;                            // 2048
    float* rq     = wv + BATCH * DSZ;              // 2048
    float* sim    = rq + BATCH * DSZ;              // 524288
    float* cand_v = sim + (size_t)BATCH * MSZ;     // 16384
    int*   cand_i = (int*)(cand_v + BATCH * NCHUNK * TOPK);   // 16384
    float* u      = (float*)(cand_i + BATCH * NCHUNK * TOPK); // 2048

    k0_proj <<<256, 256, 0, stream>>>(x, Ww, bw, Wr, br, wv, rq);
    k1_sim  <<<256, 256, 0, stream>>>(rq, memory, sim);
    k2_ptopk<<<256, 256, 0, stream>>>(sim, cand_v, cand_i);
    k3_merge<<<256, 256, 0, stream>>>(cand_v, cand_i, memory, wv, Wo, bo, out, u);
    k4_bcast<<<MSZ * DSZ / 4 / 256, 256, 0, stream>>>(memory, u, out_nm);
}